// Round 14
// baseline (166.542 us; speedup 1.0000x reference)
//
#include <hip/hip_runtime.h>
#include <hip/hip_fp16.h>
#include <math.h>

// Problem constants (from reference)
#define NN 20000          // nodes
#define TT 4              // time steps
#define EE 320000         // edges
#define NT (NN*TT)        // 80000 rows
#define H1 8              // heads layer 1
#define C1 128            // heads*f_out layer 1
#define IN_F 32
#define OUT_F 16
#define CAP 96            // bucket capacity; max degree Poisson(16) << 96
#define SCAT_BLOCKS 313   // ceil((EE/4)/256)
#define XCAST_BLOCKS 1250 // NT/64

typedef _Float16 h8 __attribute__((ext_vector_type(8)));
typedef float f32x4 __attribute__((ext_vector_type(4)));

__device__ __forceinline__ float lrelu_exp(float e) {
  e = (e >= 0.f) ? e : 0.2f * e;
  return __expf(e);
}

// ---------------------------------------------------------------------------
// K1 "front": blocks 0..312 = bucket-CSR scatter; block 313 = global weight
// prep (W1hp per-head B-frags + W2pp); blocks 314.. = x cast to fp16 +
// el1/er1 via one ELER MFMA (ELER tile built in LDS: 1 tile, cheap).
// ---------------------------------------------------------------------------
__global__ __launch_bounds__(256) void k_front(
    const float* __restrict__ x, const float* __restrict__ W1,
    const float* __restrict__ al1, const float* __restrict__ ar1,
    const float* __restrict__ W2, const float* __restrict__ al2,
    const float* __restrict__ ar2,
    const int4* __restrict__ src4, const int4* __restrict__ dst4,
    int* __restrict__ cnt, int* __restrict__ csr96,
    __half* __restrict__ xh, float* __restrict__ el1, float* __restrict__ er1,
    __half* __restrict__ W1hp, __half* __restrict__ W2pp) {
  __shared__ h8 ELERs[64];               // 1 KB, xcast branch only
  int b = blockIdx.x;
  int tid = threadIdx.x;
  if (b < SCAT_BLOCKS) {
    int e4 = b * 256 + tid;
    if (e4 < EE / 4) {
      int4 s = src4[e4];
      int4 d = dst4[e4];
      int p0 = atomicAdd(&cnt[d.x], 1); csr96[d.x * CAP + p0] = s.x;
      int p1 = atomicAdd(&cnt[d.y], 1); csr96[d.y * CAP + p1] = s.y;
      int p2 = atomicAdd(&cnt[d.z], 1); csr96[d.z * CAP + p2] = s.z;
      int p3 = atomicAdd(&cnt[d.w], 1); csr96[d.w * CAP + p3] = s.w;
    }
    return;
  }
  if (b == SCAT_BLOCKS) {
    // W1hp: 8 per-head B-frag tiles, B[k][n] with n=lane&15, k=(lane>>4)*8+j
    for (int idx = tid; idx < 8 * 512; idx += 256) {
      int tile = idx >> 9;
      int rem = idx & 511;
      int lane = rem >> 3, j = rem & 7;
      int k = (lane >> 4) * 8 + j;
      int n = lane & 15;
      W1hp[idx] = __float2half(W1[k * C1 + tile * 16 + n]);
    }
    // W2pp: 4 feat k-step tiles + 4 [Wl2|Wr2|0] k-step tiles
    for (int idx = tid; idx < 8 * 512; idx += 256) {
      int tile = idx >> 9;
      int rem = idx & 511;
      int lane = rem >> 3, j = rem & 7;
      int ks = tile & 3;
      int k = ks * 32 + (lane >> 4) * 8 + j;
      int n = lane & 15;
      float v = 0.f;
      if (tile < 4) {
        v = W2[k * OUT_F + n];
      } else if (n == 0) {
        float s = 0.f;
        for (int f = 0; f < 16; ++f) s += W2[k * OUT_F + f] * al2[f];
        v = s;
      } else if (n == 1) {
        float s = 0.f;
        for (int f = 0; f < 16; ++f) s += W2[k * OUT_F + f] * ar2[f];
        v = s;
      }
      W2pp[idx] = __float2half(v);
    }
    return;
  }
  // ---- xcast + el/er branch ----
  {
    __half* E = (__half*)ELERs;
    for (int idx = tid; idx < 512; idx += 256) {
      int lane = idx >> 3, j = idx & 7;
      int k = (lane >> 4) * 8 + j;
      int n = lane & 15;
      int hh_ = n & 7;
      const float* a = (n < 8) ? al1 : ar1;
      float s = 0.f;
      for (int f = 0; f < 16; ++f) s += W1[k * C1 + hh_ * 16 + f] * a[hh_ * 16 + f];
      E[idx] = __float2half(s);
    }
  }
  __syncthreads();
  int wave = tid >> 6, lane = tid & 63;
  int m = lane & 15, quad = lane >> 4;
  int rowbase = (b - SCAT_BLOCKS - 1) * 64 + wave * 16;
  int row = rowbase + m;
  const float4* xp = (const float4*)(x + row * IN_F + quad * 8);
  float4 a0 = xp[0], a1 = xp[1];
  h8 af;
  af[0] = (_Float16)a0.x; af[1] = (_Float16)a0.y;
  af[2] = (_Float16)a0.z; af[3] = (_Float16)a0.w;
  af[4] = (_Float16)a1.x; af[5] = (_Float16)a1.y;
  af[6] = (_Float16)a1.z; af[7] = (_Float16)a1.w;
  *(h8*)(xh + (size_t)row * IN_F + quad * 8) = af;   // fp16 x copy
  {
    h8 bf = ELERs[lane];
    f32x4 c = {0.f, 0.f, 0.f, 0.f};
    c = __builtin_amdgcn_mfma_f32_16x16x32_f16(af, bf, c, 0, 0, 0);
#pragma unroll
    for (int r = 0; r < 4; ++r) {
      int orow = rowbase + quad * 4 + r;
      if (m < 8) el1[orow * H1 + m] = c[r];
      else       er1[orow * H1 + (m - 8)] = c[r];
    }
  }
}

// ---------------------------------------------------------------------------
// K2: layer-1 x-form aggregate with LDS edge-staging. The h-dimension reuse
// (8 heads share each x fragment) made the register-resident form issue 8x
// redundant VMEM (2 KB/edge for 256 B unique). Now: 3 coalesced VMEM
// instructions stage 8 edges' x(256B)+el(128B) rows into a wave-private LDS
// slab; consumers ds_read_b128 their 32 B fragment (8-lane same-address
// broadcast = free) and ds_read_b32 the el value. No barriers (same-wave DS
// ordering). VMEM instrs per 8 edges: 24 -> 3.
// ---------------------------------------------------------------------------
__global__ __launch_bounds__(256) void k_agg1x(
    const __half* __restrict__ xh,       // [n][4t][32ch] = 128 halves/node
    const float* __restrict__ el1,       // [n][4t][8h]   = 32 floats/node
    const float* __restrict__ er1,
    const int* __restrict__ cnt, const int* __restrict__ csr96,
    __half* __restrict__ aggx) {         // [nt][8h][32]
  __shared__ __half xs[4][8][128];       // 8 KB: per wave, 8 edges x 256 B
  __shared__ float  es[4][8][32];        // 4 KB: per wave, 8 edges x 128 B
  int tid = threadIdx.x;
  int wv = tid >> 6, lane = tid & 63;
  int n = blockIdx.x * 4 + wv;
  int slot = lane >> 1;                  // (t,h): t=slot>>3, h=slot&7
  int t = lane >> 4;                     // == slot>>3
  int hf = lane & 1;
  int ej = lane >> 3;                    // edge this lane stages (0..7)
  int eo = lane & 7;                     // 32B-offset group within edge
  float er_i = er1[(size_t)n * 32 + slot];
  int deg = cnt[n];
  const int* eb = csr96 + (size_t)n * CAP;
  float acc[16];
#pragma unroll
  for (int k = 0; k < 16; ++k) acc[k] = 0.f;
  float l = 0.f;
  for (int chunk = 0; chunk < deg; chunk += 64) {
    int m = min(64, deg - chunk);
    int sv = (lane < m) ? eb[chunk + lane] : 0;
    int iters = (m + 7) >> 3;
    for (int g = 0; g < iters; ++g) {
      int j = g * 8;
      int sj = __shfl(sv, j + ej);       // source node of the staged edge
      // stage x: 32B/lane -> 8 edges x 256B, fully coalesced
      const h8* xp = (const h8*)(xh + (size_t)sj * 128 + eo * 16);
      h8 xa = xp[0], xb = xp[1];
      // stage el: 16B/lane -> 8 edges x 128B, fully coalesced
      float4 ev = *(const float4*)(el1 + (size_t)sj * 32 + eo * 4);
      *(h8*)&xs[wv][ej][eo * 16]     = xa;
      *(h8*)&xs[wv][ej][eo * 16 + 8] = xb;
      *(float4*)&es[wv][ej][eo * 4]  = ev;
      // consume: same-wave DS ordering suffices, no barrier
#pragma unroll
      for (int k = 0; k < 8; ++k) {
        float ew = es[wv][k][slot];      // 2-lane broadcast read
        float w_ = lrelu_exp(ew + er_i);
        w_ = (j + k < m) ? w_ : 0.f;
        l += w_;
        h8 fa = *(const h8*)&xs[wv][k][t * 32 + hf * 16];      // 8-lane bcast
        h8 fb = *(const h8*)&xs[wv][k][t * 32 + hf * 16 + 8];
#pragma unroll
        for (int q = 0; q < 8; ++q) {
          acc[q]     = fmaf(w_, (float)fa[q], acc[q]);
          acc[8 + q] = fmaf(w_, (float)fb[q], acc[8 + q]);
        }
      }
    }
  }
  float inv = (l > 0.f) ? (1.f / l) : 0.f;
  h8 r0, r1;
#pragma unroll
  for (int q = 0; q < 8; ++q) {
    r0[q] = (_Float16)(acc[q] * inv);
    r1[q] = (_Float16)(acc[8 + q] * inv);
  }
  int hh_ = slot & 7;
  __half* op = aggx + (size_t)(n * 4 + t) * 256 + hh_ * 32 + hf * 16;
  *(h8*)op = r0;
  *(h8*)(op + 8) = r1;
}

// ---------------------------------------------------------------------------
// K3: fused mid: h = aggx per-head GEMM (+b1) -> wave-private LDS h-tile
// (C-layout ds_write, A-layout ds_read_b128) -> feat2/el2/er2 GEMM. h never
// touches global. Both phases are throughput GEMM code — safe fusion.
// ---------------------------------------------------------------------------
__global__ __launch_bounds__(256) void k_mid2(
    const __half* __restrict__ aggx,     // [nt][8][32]
    const __half* __restrict__ W1hp, const float* __restrict__ b1,
    const __half* __restrict__ W2pp,
    __half* __restrict__ feat2h, float* __restrict__ el2, float* __restrict__ er2) {
  __shared__ __half hs[4][16][C1];       // 16 KB, wave-private tiles
  int tid = threadIdx.x;
  int wave = tid >> 6, lane = tid & 63;
  int m = lane & 15, quad = lane >> 4;
  int rowbase = blockIdx.x * 64 + wave * 16;
  const h8* bp1 = (const h8*)W1hp;
  // phase 1: h rows -> LDS (C-layout: out row quad*4+r, col hh*16+m)
#pragma unroll
  for (int hh_ = 0; hh_ < 8; ++hh_) {
    h8 af = *(const h8*)(aggx + (size_t)(rowbase + m) * 256 + hh_ * 32 + quad * 8);
    f32x4 c = {0.f, 0.f, 0.f, 0.f};
    c = __builtin_amdgcn_mfma_f32_16x16x32_f16(af, bp1[hh_ * 64 + lane], c, 0, 0, 0);
    float bv = b1[hh_ * 16 + m];
#pragma unroll
    for (int r = 0; r < 4; ++r)
      hs[wave][quad * 4 + r][hh_ * 16 + m] = __float2half(c[r] + bv);
  }
  // phase 2: LDS h-tile (A-layout reads) -> feat2 + el2/er2
  // same-wave ds ordering: no barrier needed
  const h8* bp2 = (const h8*)W2pp;
  f32x4 cF = {0.f, 0.f, 0.f, 0.f};
  f32x4 cE = {0.f, 0.f, 0.f, 0.f};
#pragma unroll
  for (int ks = 0; ks < 4; ++ks) {
    h8 af = *(const h8*)&hs[wave][m][ks * 32 + quad * 8];
    cF = __builtin_amdgcn_mfma_f32_16x16x32_f16(af, bp2[ks * 64 + lane], cF, 0, 0, 0);
    cE = __builtin_amdgcn_mfma_f32_16x16x32_f16(af, bp2[(4 + ks) * 64 + lane], cE, 0, 0, 0);
  }
#pragma unroll
  for (int r = 0; r < 4; ++r) {
    int orow = rowbase + quad * 4 + r;
    feat2h[(size_t)orow * OUT_F + m] = __float2half(cF[r]);
    if (m == 0) el2[orow] = cE[r];
    if (m == 1) er2[orow] = cE[r];
  }
}

// ---------------------------------------------------------------------------
// K4: layer-2 aggregate, no-routing form. One wave per node; lane owns
// (t = lane>>4, f = lane&15); alpha computed locally; 8-edge batches
// (cheap per-edge state here: VGPR stays low, unlike agg1x).
// ---------------------------------------------------------------------------
__global__ __launch_bounds__(256) void k_agg2x(
    const __half* __restrict__ feat2h,   // [nt][16]
    const float* __restrict__ el2, const float* __restrict__ er2,  // [nt]
    const int* __restrict__ cnt, const int* __restrict__ csr96,
    const float* __restrict__ b2, float* __restrict__ out) {
  int tid = threadIdx.x;
  int wv = tid >> 6, lane = tid & 63;
  int n = blockIdx.x * 4 + wv;
  int t = lane >> 4, f = lane & 15;
  float ern = er2[n * 4 + t];
  int deg = cnt[n];
  const int* eb = csr96 + (size_t)n * CAP;
  float acc = 0.f, l = 0.f;
  for (int chunk = 0; chunk < deg; chunk += 64) {
    int m = min(64, deg - chunk);
    int sv = (lane < m) ? eb[chunk + lane] : 0;
    int iters = (m + 7) >> 3;
    for (int g = 0; g < iters; ++g) {
      int j = g * 8;
      int s0 = __builtin_amdgcn_readlane(sv, j + 0);
      int s1 = __builtin_amdgcn_readlane(sv, j + 1);
      int s2 = __builtin_amdgcn_readlane(sv, j + 2);
      int s3 = __builtin_amdgcn_readlane(sv, j + 3);
      int s4 = __builtin_amdgcn_readlane(sv, j + 4);
      int s5 = __builtin_amdgcn_readlane(sv, j + 5);
      int s6 = __builtin_amdgcn_readlane(sv, j + 6);
      int s7 = __builtin_amdgcn_readlane(sv, j + 7);
      float e0 = el2[s0 * 4 + t];
      float e1 = el2[s1 * 4 + t];
      float e2 = el2[s2 * 4 + t];
      float e3 = el2[s3 * 4 + t];
      float e4 = el2[s4 * 4 + t];
      float e5 = el2[s5 * 4 + t];
      float e6 = el2[s6 * 4 + t];
      float e7 = el2[s7 * 4 + t];
      __half f0 = feat2h[(size_t)(s0 * 4 + t) * OUT_F + f];
      __half f1 = feat2h[(size_t)(s1 * 4 + t) * OUT_F + f];
      __half f2 = feat2h[(size_t)(s2 * 4 + t) * OUT_F + f];
      __half f3 = feat2h[(size_t)(s3 * 4 + t) * OUT_F + f];
      __half f4 = feat2h[(size_t)(s4 * 4 + t) * OUT_F + f];
      __half f5 = feat2h[(size_t)(s5 * 4 + t) * OUT_F + f];
      __half f6 = feat2h[(size_t)(s6 * 4 + t) * OUT_F + f];
      __half f7 = feat2h[(size_t)(s7 * 4 + t) * OUT_F + f];
#define CONSUME(K, EW, FV)                                        \
      {                                                           \
        float w_ = lrelu_exp(EW + ern);                           \
        w_ = (j + K < m) ? w_ : 0.f;                              \
        l += w_;                                                  \
        acc = fmaf(w_, __half2float(FV), acc);                    \
      }
      CONSUME(0, e0, f0) CONSUME(1, e1, f1)
      CONSUME(2, e2, f2) CONSUME(3, e3, f3)
      CONSUME(4, e4, f4) CONSUME(5, e5, f5)
      CONSUME(6, e6, f6) CONSUME(7, e7, f7)
#undef CONSUME
    }
  }
  float inv = (l > 0.f) ? (1.f / l) : 0.f;
  out[(size_t)(n * 4 + t) * OUT_F + f] = acc * inv + b2[f];
}

// ---------------------------------------------------------------------------
extern "C" void kernel_launch(void* const* d_in, const int* in_sizes, int n_in,
                              void* d_out, int out_size, void* d_ws, size_t ws_size,
                              hipStream_t stream) {
  const float* x   = (const float*)d_in[0];
  const int*   src = (const int*)d_in[1];
  const int*   dst = (const int*)d_in[2];
  const float* W1  = (const float*)d_in[3];
  const float* al1 = (const float*)d_in[4];
  const float* ar1 = (const float*)d_in[5];
  const float* b1  = (const float*)d_in[6];
  const float* W2  = (const float*)d_in[7];
  const float* al2 = (const float*)d_in[8];
  const float* ar2 = (const float*)d_in[9];
  const float* b2  = (const float*)d_in[10];
  float* out = (float*)d_out;

  // Workspace layout (bytes, 256-aligned chunks), ~63 MB total
  char* w = (char*)d_ws;
  __half* xh     = (__half*)w; w += (size_t)NT * IN_F * 2;      // 5.12 MB
  __half* aggx   = (__half*)w; w += (size_t)NT * 256 * 2;       // 40.96 MB
  __half* feat2h = (__half*)w; w += (size_t)NT * OUT_F * 2;     // 2.56 MB
  float*  el1    = (float*)w;  w += (size_t)NT * H1 * 4;        // 2.56 MB
  float*  er1    = (float*)w;  w += (size_t)NT * H1 * 4;
  float*  el2    = (float*)w;  w += (size_t)NT * 4;             // 0.32 MB
  float*  er2    = (float*)w;  w += (size_t)NT * 4;
  __half* W1hp   = (__half*)w; w += (size_t)8 * 512 * 2;
  __half* W2pp   = (__half*)w; w += (size_t)8 * 512 * 2;
  int* cnt     = (int*)w;      w += (size_t)NN * 4;             // 80 KB
  int* csr96   = (int*)w;      w += (size_t)NN * CAP * 4;       // 7.68 MB

  hipMemsetAsync(cnt, 0, NN * sizeof(int), stream);

  k_front<<<SCAT_BLOCKS + 1 + XCAST_BLOCKS, 256, 0, stream>>>(
      x, W1, al1, ar1, W2, al2, ar2, (const int4*)src, (const int4*)dst,
      cnt, csr96, xh, el1, er1, W1hp, W2pp);
  k_agg1x<<<NN / 4, 256, 0, stream>>>(xh, el1, er1, cnt, csr96, aggx);
  k_mid2<<<NT / 64, 256, 0, stream>>>(aggx, W1hp, b1, W2pp, feat2h, el2, er2);
  k_agg2x<<<NN / 4, 256, 0, stream>>>(feat2h, el2, er2, cnt, csr96, b2, out);
}